// Round 1
// baseline (911.484 us; speedup 1.0000x reference)
//
#include <hip/hip_runtime.h>
#include <hip/hip_bf16.h>

typedef __bf16 bf16;
typedef __attribute__((ext_vector_type(4))) __bf16 bf16x4;
typedef __attribute__((ext_vector_type(8))) __bf16 bf16x8;
typedef __attribute__((ext_vector_type(4))) float floatx4;

#define BB 8
#define NN 4096
#define MM 2048
#define DD 256
#define DV 256

// ---------------------------------------------------------------------------
// Kernel 1: transpose v [B][M][DV] fp32 -> vT [B][DV][M] bf16 (in d_ws)
// 64x64 tiles through LDS; coalesced global read and write.
// ---------------------------------------------------------------------------
__global__ __launch_bounds__(256) void vtrans_kernel(const float* __restrict__ v,
                                                     bf16* __restrict__ vT) {
    const int b  = blockIdx.z;
    const int m0 = blockIdx.y * 64;
    const int d0 = blockIdx.x * 64;
    __shared__ float Ts[64][65];
    const int t  = threadIdx.x;
    const int cf = t & 15;   // float4 column index (16 per 64-wide row)
    const int r  = t >> 4;   // 16 rows per pass

    const float* vb = v + ((size_t)b * MM + m0) * DV + d0;
    for (int p = 0; p < 4; ++p) {
        int row = p * 16 + r;
        float4 x = *(const float4*)(vb + (size_t)row * DV + cf * 4);
        Ts[row][cf * 4 + 0] = x.x;
        Ts[row][cf * 4 + 1] = x.y;
        Ts[row][cf * 4 + 2] = x.z;
        Ts[row][cf * 4 + 3] = x.w;
    }
    __syncthreads();
    bf16* ob = vT + ((size_t)b * DV + d0) * MM + m0;
    for (int p = 0; p < 4; ++p) {
        int dv = p * 16 + r;
        bf16x4 w;
        for (int i = 0; i < 4; ++i) w[i] = (bf16)Ts[cf * 4 + i][dv];
        *(bf16x4*)(ob + (size_t)dv * MM + cf * 4) = w;
    }
}

// ---------------------------------------------------------------------------
// Kernel 2: S = (q/16) @ k^T  -> fp32 raw logits into attn region of d_out
// 128x128 tile, TK=64, bf16 MFMA 16x16x32, 256 threads (2x2 waves of 64x64).
// ---------------------------------------------------------------------------
__global__ __launch_bounds__(256) void qk_kernel(const float* __restrict__ q,
                                                 const float* __restrict__ k,
                                                 float* __restrict__ S) {
    const int b  = blockIdx.z;
    const int n0 = blockIdx.y * 128;
    const int m0 = blockIdx.x * 128;

    __shared__ bf16 As[128][72];  // row stride 144 B (16B-aligned, conflict-free)
    __shared__ bf16 Bs[128][72];

    const int tid  = threadIdx.x;
    const int lane = tid & 63;
    const int wave = tid >> 6;
    const int wr   = (wave & 1) * 64;
    const int wc   = (wave >> 1) * 64;
    const int l15  = lane & 15;
    const int quad = lane >> 4;

    floatx4 acc[4][4] = {};

    const float* qb = q + ((size_t)b * NN + n0) * DD;
    const float* kb = k + ((size_t)b * MM + m0) * DD;

    const int cf = tid & 15;  // float4 col within 64-wide K chunk
    const int rr = tid >> 4;  // 16 rows per pass

    for (int k0 = 0; k0 < DD; k0 += 64) {
        __syncthreads();
        for (int p = 0; p < 8; ++p) {
            int row = p * 16 + rr;
            float4 aq = *(const float4*)(qb + (size_t)row * DD + k0 + cf * 4);
            float4 bk = *(const float4*)(kb + (size_t)row * DD + k0 + cf * 4);
            bf16x4 wa, wb;
            wa[0] = (bf16)(aq.x * 0.0625f);
            wa[1] = (bf16)(aq.y * 0.0625f);
            wa[2] = (bf16)(aq.z * 0.0625f);
            wa[3] = (bf16)(aq.w * 0.0625f);
            wb[0] = (bf16)bk.x;
            wb[1] = (bf16)bk.y;
            wb[2] = (bf16)bk.z;
            wb[3] = (bf16)bk.w;
            *(bf16x4*)&As[row][cf * 4] = wa;
            *(bf16x4*)&Bs[row][cf * 4] = wb;
        }
        __syncthreads();
        for (int kk = 0; kk < 64; kk += 32) {
            bf16x8 af[4], bfv[4];
            for (int i = 0; i < 4; ++i)
                af[i] = *(const bf16x8*)&As[wr + i * 16 + l15][kk + quad * 8];
            for (int j = 0; j < 4; ++j)
                bfv[j] = *(const bf16x8*)&Bs[wc + j * 16 + l15][kk + quad * 8];
            for (int i = 0; i < 4; ++i)
                for (int j = 0; j < 4; ++j)
                    acc[i][j] = __builtin_amdgcn_mfma_f32_16x16x32_bf16(
                        af[i], bfv[j], acc[i][j], 0, 0, 0);
        }
    }

    float* Sb = S + ((size_t)b * NN + n0) * MM + m0;
    for (int i = 0; i < 4; ++i)
        for (int j = 0; j < 4; ++j) {
            int gc = wc + j * 16 + l15;
            for (int r = 0; r < 4; ++r) {
                int gr = wr + i * 16 + quad * 4 + r;
                Sb[(size_t)gr * MM + gc] = acc[i][j][r];
            }
        }
}

// ---------------------------------------------------------------------------
// Kernel 3: per-row: attn = softmax(mask ? S : -1e9) + softmax(oa), in place.
// One 256-thread block per row (B*N rows), 8 elements/thread, all float4.
// ---------------------------------------------------------------------------
__global__ __launch_bounds__(256) void softmax_add_kernel(const float* __restrict__ oa,
                                                          const int* __restrict__ mask,
                                                          float* __restrict__ attn) {
    const size_t base = (size_t)blockIdx.x * MM;
    const int t    = threadIdx.x;
    const int lane = t & 63;
    const int wv   = t >> 6;

    __shared__ float redS[4], redO[4];

    float s[8], o[8];
    for (int c = 0; c < 2; ++c) {
        float4 s4 = *(const float4*)(attn + base + c * 1024 + t * 4);
        int4   m4 = *(const int4*)(mask + base + c * 1024 + t * 4);
        float4 o4 = *(const float4*)(oa + base + c * 1024 + t * 4);
        s[c * 4 + 0] = m4.x ? s4.x : -1e9f;
        s[c * 4 + 1] = m4.y ? s4.y : -1e9f;
        s[c * 4 + 2] = m4.z ? s4.z : -1e9f;
        s[c * 4 + 3] = m4.w ? s4.w : -1e9f;
        o[c * 4 + 0] = o4.x;
        o[c * 4 + 1] = o4.y;
        o[c * 4 + 2] = o4.z;
        o[c * 4 + 3] = o4.w;
    }

    float mxs = s[0], mxo = o[0];
    for (int i = 1; i < 8; ++i) {
        mxs = fmaxf(mxs, s[i]);
        mxo = fmaxf(mxo, o[i]);
    }
    for (int off = 32; off >= 1; off >>= 1) {
        mxs = fmaxf(mxs, __shfl_xor(mxs, off, 64));
        mxo = fmaxf(mxo, __shfl_xor(mxo, off, 64));
    }
    if (lane == 0) { redS[wv] = mxs; redO[wv] = mxo; }
    __syncthreads();
    mxs = fmaxf(fmaxf(redS[0], redS[1]), fmaxf(redS[2], redS[3]));
    mxo = fmaxf(fmaxf(redO[0], redO[1]), fmaxf(redO[2], redO[3]));
    __syncthreads();

    float sums = 0.f, sumo = 0.f;
    for (int i = 0; i < 8; ++i) {
        s[i] = __expf(s[i] - mxs);
        o[i] = __expf(o[i] - mxo);
        sums += s[i];
        sumo += o[i];
    }
    for (int off = 32; off >= 1; off >>= 1) {
        sums += __shfl_xor(sums, off, 64);
        sumo += __shfl_xor(sumo, off, 64);
    }
    if (lane == 0) { redS[wv] = sums; redO[wv] = sumo; }
    __syncthreads();
    sums = redS[0] + redS[1] + redS[2] + redS[3];
    sumo = redO[0] + redO[1] + redO[2] + redO[3];

    const float invs = 1.0f / sums;
    const float invo = 1.0f / sumo;
    for (int c = 0; c < 2; ++c) {
        float4 w;
        w.x = s[c * 4 + 0] * invs + o[c * 4 + 0] * invo;
        w.y = s[c * 4 + 1] * invs + o[c * 4 + 1] * invo;
        w.z = s[c * 4 + 2] * invs + o[c * 4 + 2] * invo;
        w.w = s[c * 4 + 3] * invs + o[c * 4 + 3] * invo;
        *(float4*)(attn + base + c * 1024 + t * 4) = w;
    }
}

// ---------------------------------------------------------------------------
// Kernel 4: out = attn @ v   ([N x M] @ [M x DV] per batch)
// 128x128 tile, TK=64, attn fp32->bf16 in staging, v from pre-transposed vT.
// ---------------------------------------------------------------------------
__global__ __launch_bounds__(256) void pv_kernel(const float* __restrict__ attn,
                                                 const bf16* __restrict__ vT,
                                                 float* __restrict__ out) {
    const int b  = blockIdx.z;
    const int n0 = blockIdx.y * 128;
    const int d0 = blockIdx.x * 128;

    __shared__ bf16 As[128][72];
    __shared__ bf16 Bs[128][72];

    const int tid  = threadIdx.x;
    const int lane = tid & 63;
    const int wave = tid >> 6;
    const int wr   = (wave & 1) * 64;
    const int wc   = (wave >> 1) * 64;
    const int l15  = lane & 15;
    const int quad = lane >> 4;

    floatx4 acc[4][4] = {};

    const float* ab  = attn + ((size_t)b * NN + n0) * MM;
    const bf16*  vtb = vT + ((size_t)b * DV + d0) * MM;

    const int cf  = tid & 15;  // for attn staging: float4 col in 64-wide chunk
    const int rr  = tid >> 4;  // 16 rows per pass
    const int seg = tid & 1;   // for vT staging: half-row
    const int vr  = tid >> 1;  // vT row (0..127)

    for (int k0 = 0; k0 < MM; k0 += 64) {
        __syncthreads();
        // stage attn tile 128x64 fp32 -> bf16
        for (int p = 0; p < 8; ++p) {
            int row = p * 16 + rr;
            float4 a4 = *(const float4*)(ab + (size_t)row * MM + k0 + cf * 4);
            bf16x4 w;
            w[0] = (bf16)a4.x;
            w[1] = (bf16)a4.y;
            w[2] = (bf16)a4.z;
            w[3] = (bf16)a4.w;
            *(bf16x4*)&As[row][cf * 4] = w;
        }
        // stage vT tile 128x64 bf16 (already transposed: row = dv, col = m)
        {
            const bf16* src = vtb + (size_t)vr * MM + k0 + seg * 32;
            for (int h = 0; h < 4; ++h) {
                bf16x8 w = *(const bf16x8*)(src + h * 8);
                *(bf16x8*)&Bs[vr][seg * 32 + h * 8] = w;
            }
        }
        __syncthreads();
        for (int kk = 0; kk < 64; kk += 32) {
            bf16x8 af[4], bfv[4];
            for (int i = 0; i < 4; ++i)
                af[i] = *(const bf16x8*)&As[wr + i * 16 + l15][kk + quad * 8];
            for (int j = 0; j < 4; ++j)
                bfv[j] = *(const bf16x8*)&Bs[wc + j * 16 + l15][kk + quad * 8];
            for (int i = 0; i < 4; ++i)
                for (int j = 0; j < 4; ++j)
                    acc[i][j] = __builtin_amdgcn_mfma_f32_16x16x32_bf16(
                        af[i], bfv[j], acc[i][j], 0, 0, 0);
        }
    }

    float* ob = out + ((size_t)b * NN + n0) * DV + d0;
    for (int i = 0; i < 4; ++i)
        for (int j = 0; j < 4; ++j) {
            int gc = wc + j * 16 + l15;
            for (int r = 0; r < 4; ++r) {
                int gr = wr + i * 16 + quad * 4 + r;
                ob[(size_t)gr * DV + gc] = acc[i][j][r];
            }
        }
}

extern "C" void kernel_launch(void* const* d_in, const int* in_sizes, int n_in,
                              void* d_out, int out_size, void* d_ws, size_t ws_size,
                              hipStream_t stream) {
    const float* q    = (const float*)d_in[0];
    const float* k    = (const float*)d_in[1];
    const float* v    = (const float*)d_in[2];
    const float* oa   = (const float*)d_in[3];
    const int*   mask = (const int*)d_in[4];
    // d_in[5] = feature (always 1 in setup) -> no permute of orginal_attention

    float* out  = (float*)d_out;
    float* attn = out + (size_t)BB * NN * DV;  // raw S, then final attn (in place)
    bf16*  vT   = (bf16*)d_ws;                 // 8 MB: [B][DV][M] bf16

    vtrans_kernel<<<dim3(DV / 64, MM / 64, BB), 256, 0, stream>>>(v, vT);
    qk_kernel<<<dim3(MM / 128, NN / 128, BB), 256, 0, stream>>>(q, k, attn);
    softmax_add_kernel<<<BB * NN, 256, 0, stream>>>(oa, mask, attn);
    pv_kernel<<<dim3(DV / 128, NN / 128, BB), 256, 0, stream>>>(attn, vT, out);
}

// Round 2
// 871.955 us; speedup vs baseline: 1.0453x; 1.0453x over previous
//
#include <hip/hip_runtime.h>
#include <hip/hip_bf16.h>

typedef __bf16 bf16;
typedef __attribute__((ext_vector_type(4))) __bf16 bf16x4;
typedef __attribute__((ext_vector_type(8))) __bf16 bf16x8;
typedef __attribute__((ext_vector_type(4))) float floatx4;

#define BB 8
#define NN 4096
#define MM 2048
#define DD 256
#define DV 256

// async 16B global -> LDS (wave-uniform LDS base + lane*16 placement)
__device__ __forceinline__ void async_copy16(const void* g, void* l) {
    __builtin_amdgcn_global_load_lds(
        (const __attribute__((address_space(1))) unsigned int*)g,
        (__attribute__((address_space(3))) unsigned int*)l, 16, 0, 0);
}

// ---------------------------------------------------------------------------
// Kernel 1: transpose v [B][M][DV] fp32 -> vT [B][DV][M] bf16 (in d_ws)
// ---------------------------------------------------------------------------
__global__ __launch_bounds__(256) void vtrans_kernel(const float* __restrict__ v,
                                                     bf16* __restrict__ vT) {
    const int b  = blockIdx.z;
    const int m0 = blockIdx.y * 64;
    const int d0 = blockIdx.x * 64;
    __shared__ float Ts[64][65];
    const int t  = threadIdx.x;
    const int cf = t & 15;
    const int r  = t >> 4;

    const float* vb = v + ((size_t)b * MM + m0) * DV + d0;
    for (int p = 0; p < 4; ++p) {
        int row = p * 16 + r;
        float4 x = *(const float4*)(vb + (size_t)row * DV + cf * 4);
        Ts[row][cf * 4 + 0] = x.x;
        Ts[row][cf * 4 + 1] = x.y;
        Ts[row][cf * 4 + 2] = x.z;
        Ts[row][cf * 4 + 3] = x.w;
    }
    __syncthreads();
    bf16* ob = vT + ((size_t)b * DV + d0) * MM + m0;
    for (int p = 0; p < 4; ++p) {
        int dv = p * 16 + r;
        bf16x4 w;
        for (int i = 0; i < 4; ++i) w[i] = (bf16)Ts[cf * 4 + i][dv];
        *(bf16x4*)(ob + (size_t)dv * MM + cf * 4) = w;
    }
}

// ---------------------------------------------------------------------------
// Kernel 1b: elementwise fp32 -> bf16 with scale (for q/16 and k)
// ---------------------------------------------------------------------------
__global__ __launch_bounds__(256) void conv_kernel(const float* __restrict__ src,
                                                   bf16* __restrict__ dst,
                                                   float scale) {
    size_t i = ((size_t)blockIdx.x * 256 + threadIdx.x) * 8;
    float4 a = *(const float4*)(src + i);
    float4 b = *(const float4*)(src + i + 4);
    bf16x8 w;
    w[0] = (bf16)(a.x * scale); w[1] = (bf16)(a.y * scale);
    w[2] = (bf16)(a.z * scale); w[3] = (bf16)(a.w * scale);
    w[4] = (bf16)(b.x * scale); w[5] = (bf16)(b.y * scale);
    w[6] = (bf16)(b.z * scale); w[7] = (bf16)(b.w * scale);
    *(bf16x8*)(dst + i) = w;
}

// ---------------------------------------------------------------------------
// Kernel 2 (fast): S = qbf @ kbf^T, both operands pre-converted bf16 in ws.
// m97-style: global_load_lds width-16 into unpadded [128][64] LDS tiles.
// ---------------------------------------------------------------------------
__global__ __launch_bounds__(256) void qk_fast_kernel(const bf16* __restrict__ qbf,
                                                      const bf16* __restrict__ kbf,
                                                      float* __restrict__ S) {
    const int b  = blockIdx.z;
    const int n0 = blockIdx.y * 128;
    const int m0 = blockIdx.x * 128;

    __shared__ bf16 As[128 * 64];
    __shared__ bf16 Bs[128 * 64];

    const int tid  = threadIdx.x;
    const int lane = tid & 63;
    const int wave = tid >> 6;
    const int wr   = (wave & 1) * 64;
    const int wc   = (wave >> 1) * 64;
    const int l15  = lane & 15;
    const int quad = lane >> 4;

    floatx4 acc[4][4] = {};

    const bf16* qb = qbf + ((size_t)b * NN + n0) * DD;
    const bf16* kb = kbf + ((size_t)b * MM + m0) * DD;

    const int lrow = lane >> 3;        // 0..7
    const int lcol = (lane & 7) * 8;   // elem col within 64-chunk

    for (int k0 = 0; k0 < DD; k0 += 64) {
        __syncthreads();
        for (int p = 0; p < 4; ++p) {
            int seg = wave * 4 + p;            // 0..15
            int row = seg * 8 + lrow;          // 0..127
            async_copy16(qb + (size_t)row * DD + k0 + lcol, &As[seg * 512]);
            async_copy16(kb + (size_t)row * DD + k0 + lcol, &Bs[seg * 512]);
        }
        __syncthreads();
        for (int kk = 0; kk < 64; kk += 32) {
            bf16x8 af[4], bfv[4];
            for (int i = 0; i < 4; ++i)
                af[i] = *(const bf16x8*)&As[(wr + i * 16 + l15) * 64 + kk + quad * 8];
            for (int j = 0; j < 4; ++j)
                bfv[j] = *(const bf16x8*)&Bs[(wc + j * 16 + l15) * 64 + kk + quad * 8];
            for (int i = 0; i < 4; ++i)
                for (int j = 0; j < 4; ++j)
                    acc[i][j] = __builtin_amdgcn_mfma_f32_16x16x32_bf16(
                        af[i], bfv[j], acc[i][j], 0, 0, 0);
        }
    }

    float* Sb = S + ((size_t)b * NN + n0) * MM + m0;
    for (int i = 0; i < 4; ++i)
        for (int j = 0; j < 4; ++j) {
            int gc = wc + j * 16 + l15;
            for (int r = 0; r < 4; ++r) {
                int gr = wr + i * 16 + quad * 4 + r;
                Sb[(size_t)gr * MM + gc] = acc[i][j][r];
            }
        }
}

// ---------------------------------------------------------------------------
// Kernel 2 (fallback, ws too small): fp32 inputs staged with VALU convert.
// ---------------------------------------------------------------------------
__global__ __launch_bounds__(256) void qk_kernel(const float* __restrict__ q,
                                                 const float* __restrict__ k,
                                                 float* __restrict__ S) {
    const int b  = blockIdx.z;
    const int n0 = blockIdx.y * 128;
    const int m0 = blockIdx.x * 128;

    __shared__ bf16 As[128][72];
    __shared__ bf16 Bs[128][72];

    const int tid  = threadIdx.x;
    const int lane = tid & 63;
    const int wave = tid >> 6;
    const int wr   = (wave & 1) * 64;
    const int wc   = (wave >> 1) * 64;
    const int l15  = lane & 15;
    const int quad = lane >> 4;

    floatx4 acc[4][4] = {};

    const float* qb = q + ((size_t)b * NN + n0) * DD;
    const float* kb = k + ((size_t)b * MM + m0) * DD;

    const int cf = tid & 15;
    const int rr = tid >> 4;

    for (int k0 = 0; k0 < DD; k0 += 64) {
        __syncthreads();
        for (int p = 0; p < 8; ++p) {
            int row = p * 16 + rr;
            float4 aq = *(const float4*)(qb + (size_t)row * DD + k0 + cf * 4);
            float4 bk = *(const float4*)(kb + (size_t)row * DD + k0 + cf * 4);
            bf16x4 wa, wb;
            wa[0] = (bf16)(aq.x * 0.0625f);
            wa[1] = (bf16)(aq.y * 0.0625f);
            wa[2] = (bf16)(aq.z * 0.0625f);
            wa[3] = (bf16)(aq.w * 0.0625f);
            wb[0] = (bf16)bk.x;
            wb[1] = (bf16)bk.y;
            wb[2] = (bf16)bk.z;
            wb[3] = (bf16)bk.w;
            *(bf16x4*)&As[row][cf * 4] = wa;
            *(bf16x4*)&Bs[row][cf * 4] = wb;
        }
        __syncthreads();
        for (int kk = 0; kk < 64; kk += 32) {
            bf16x8 af[4], bfv[4];
            for (int i = 0; i < 4; ++i)
                af[i] = *(const bf16x8*)&As[wr + i * 16 + l15][kk + quad * 8];
            for (int j = 0; j < 4; ++j)
                bfv[j] = *(const bf16x8*)&Bs[wc + j * 16 + l15][kk + quad * 8];
            for (int i = 0; i < 4; ++i)
                for (int j = 0; j < 4; ++j)
                    acc[i][j] = __builtin_amdgcn_mfma_f32_16x16x32_bf16(
                        af[i], bfv[j], acc[i][j], 0, 0, 0);
        }
    }

    float* Sb = S + ((size_t)b * NN + n0) * MM + m0;
    for (int i = 0; i < 4; ++i)
        for (int j = 0; j < 4; ++j) {
            int gc = wc + j * 16 + l15;
            for (int r = 0; r < 4; ++r) {
                int gr = wr + i * 16 + quad * 4 + r;
                Sb[(size_t)gr * MM + gc] = acc[i][j][r];
            }
        }
}

// ---------------------------------------------------------------------------
// Kernel 3: attn = softmax(mask ? S : -1e9) + softmax(oa), in place.
// ONE WAVE PER ROW: 64 lanes x 32 elem, no barriers, no LDS, shuffle-only.
// ---------------------------------------------------------------------------
__global__ __launch_bounds__(256) void softmax_add_kernel(const float* __restrict__ oa,
                                                          const int* __restrict__ mask,
                                                          float* __restrict__ attn) {
    const int lane = threadIdx.x & 63;
    const int wv   = threadIdx.x >> 6;
    const size_t base = ((size_t)blockIdx.x * 4 + wv) * MM;

    float s[32], o[32];
#pragma unroll
    for (int c = 0; c < 8; ++c) {
        const size_t off = base + c * 256 + lane * 4;
        float4 s4 = *(const float4*)(attn + off);
        int4   m4 = *(const int4*)(mask + off);
        float4 o4 = *(const float4*)(oa + off);
        s[c * 4 + 0] = m4.x ? s4.x : -1e9f;
        s[c * 4 + 1] = m4.y ? s4.y : -1e9f;
        s[c * 4 + 2] = m4.z ? s4.z : -1e9f;
        s[c * 4 + 3] = m4.w ? s4.w : -1e9f;
        o[c * 4 + 0] = o4.x;
        o[c * 4 + 1] = o4.y;
        o[c * 4 + 2] = o4.z;
        o[c * 4 + 3] = o4.w;
    }

    float mxs = s[0], mxo = o[0];
#pragma unroll
    for (int i = 1; i < 32; ++i) {
        mxs = fmaxf(mxs, s[i]);
        mxo = fmaxf(mxo, o[i]);
    }
#pragma unroll
    for (int off = 32; off >= 1; off >>= 1) {
        mxs = fmaxf(mxs, __shfl_xor(mxs, off, 64));
        mxo = fmaxf(mxo, __shfl_xor(mxo, off, 64));
    }

    float sums = 0.f, sumo = 0.f;
#pragma unroll
    for (int i = 0; i < 32; ++i) {
        s[i] = __expf(s[i] - mxs);
        o[i] = __expf(o[i] - mxo);
        sums += s[i];
        sumo += o[i];
    }
#pragma unroll
    for (int off = 32; off >= 1; off >>= 1) {
        sums += __shfl_xor(sums, off, 64);
        sumo += __shfl_xor(sumo, off, 64);
    }

    const float invs = 1.0f / sums;
    const float invo = 1.0f / sumo;
#pragma unroll
    for (int c = 0; c < 8; ++c) {
        float4 w;
        w.x = s[c * 4 + 0] * invs + o[c * 4 + 0] * invo;
        w.y = s[c * 4 + 1] * invs + o[c * 4 + 1] * invo;
        w.z = s[c * 4 + 2] * invs + o[c * 4 + 2] * invo;
        w.w = s[c * 4 + 3] * invs + o[c * 4 + 3] * invo;
        *(float4*)(attn + base + c * 256 + lane * 4) = w;
    }
}

// ---------------------------------------------------------------------------
// Kernel 4: out = attn @ v.  64(n) x 256(full DV) tile, 256 threads.
// attn read ONCE (fp32 -> bf16 in staging); vT staged via global_load_lds.
// ---------------------------------------------------------------------------
__global__ __launch_bounds__(256) void pv_kernel(const float* __restrict__ attn,
                                                 const bf16* __restrict__ vT,
                                                 float* __restrict__ out) {
    const int b  = blockIdx.y;
    const int n0 = blockIdx.x * 64;

    __shared__ bf16 As[64][72];     // padded: VALU-staged
    __shared__ bf16 Bs[256 * 64];   // unpadded: async-staged (dv-major)

    const int tid  = threadIdx.x;
    const int lane = tid & 63;
    const int wave = tid >> 6;
    const int wc   = wave * 64;     // dv quarter per wave
    const int l15  = lane & 15;
    const int quad = lane >> 4;

    floatx4 acc[4][4] = {};

    const float* ab  = attn + ((size_t)b * NN + n0) * MM;
    const bf16*  vtb = vT + (size_t)b * DV * MM;

    const int cf   = tid & 15;
    const int rr   = tid >> 4;
    const int lrow = lane >> 3;
    const int lcol = (lane & 7) * 8;

    for (int k0 = 0; k0 < MM; k0 += 64) {
        __syncthreads();
        // stage attn 64x64 fp32 -> bf16 (4 rows-of-16 passes)
        for (int p = 0; p < 4; ++p) {
            int row = p * 16 + rr;
            float4 a4 = *(const float4*)(ab + (size_t)row * MM + k0 + cf * 4);
            bf16x4 w;
            w[0] = (bf16)a4.x;
            w[1] = (bf16)a4.y;
            w[2] = (bf16)a4.z;
            w[3] = (bf16)a4.w;
            *(bf16x4*)&As[row][cf * 4] = w;
        }
        // stage vT 256x64 bf16 via async 16B copies (8 issues per wave)
        for (int p = 0; p < 8; ++p) {
            int seg = wave * 8 + p;            // 0..31
            int dvr = seg * 8 + lrow;          // 0..255
            async_copy16(vtb + (size_t)dvr * MM + k0 + lcol, &Bs[seg * 512]);
        }
        __syncthreads();
        for (int kk = 0; kk < 64; kk += 32) {
            bf16x8 af[4], bfv[4];
            for (int i = 0; i < 4; ++i)
                af[i] = *(const bf16x8*)&As[i * 16 + l15][kk + quad * 8];
            for (int j = 0; j < 4; ++j)
                bfv[j] = *(const bf16x8*)&Bs[(wc + j * 16 + l15) * 64 + kk + quad * 8];
            for (int i = 0; i < 4; ++i)
                for (int j = 0; j < 4; ++j)
                    acc[i][j] = __builtin_amdgcn_mfma_f32_16x16x32_bf16(
                        af[i], bfv[j], acc[i][j], 0, 0, 0);
        }
    }

    float* ob = out + ((size_t)b * NN + n0) * DV;
    for (int i = 0; i < 4; ++i)
        for (int j = 0; j < 4; ++j) {
            int gc = wc + j * 16 + l15;
            for (int r = 0; r < 4; ++r) {
                int gr = i * 16 + quad * 4 + r;
                ob[(size_t)gr * DV + gc] = acc[i][j][r];
            }
        }
}

extern "C" void kernel_launch(void* const* d_in, const int* in_sizes, int n_in,
                              void* d_out, int out_size, void* d_ws, size_t ws_size,
                              hipStream_t stream) {
    const float* q    = (const float*)d_in[0];
    const float* k    = (const float*)d_in[1];
    const float* v    = (const float*)d_in[2];
    const float* oa   = (const float*)d_in[3];
    const int*   mask = (const int*)d_in[4];

    float* out  = (float*)d_out;
    float* attn = out + (size_t)BB * NN * DV;  // raw S, then final attn (in place)

    // ws layout: vT (8 MB) | qbf (16 MB) | kbf (8 MB)
    bf16* vT  = (bf16*)d_ws;
    bf16* qbf = (bf16*)((char*)d_ws + (size_t)8 * 1024 * 1024);
    bf16* kbf = (bf16*)((char*)d_ws + (size_t)24 * 1024 * 1024);
    const bool fast = ws_size >= (size_t)32 * 1024 * 1024;

    vtrans_kernel<<<dim3(DV / 64, MM / 64, BB), 256, 0, stream>>>(v, vT);
    if (fast) {
        conv_kernel<<<(BB * NN * DD / 8 + 255) / 256, 256, 0, stream>>>(q, qbf, 0.0625f);
        conv_kernel<<<(BB * MM * DD / 8 + 255) / 256, 256, 0, stream>>>(k, kbf, 1.0f);
        qk_fast_kernel<<<dim3(MM / 128, NN / 128, BB), 256, 0, stream>>>(qbf, kbf, attn);
    } else {
        qk_kernel<<<dim3(MM / 128, NN / 128, BB), 256, 0, stream>>>(q, k, attn);
    }
    softmax_add_kernel<<<BB * NN / 4, 256, 0, stream>>>(oa, mask, attn);
    pv_kernel<<<dim3(NN / 64, BB), 256, 0, stream>>>(attn, vT, out);
}